// Round 1
// baseline (147.934 us; speedup 1.0000x reference)
//
#include <hip/hip_runtime.h>

// WassersteinLoss: out = scale * sum_{b,c,t} |a-b| * (T - t)
// R8: TRIPLE-path streaming reader.
// Prior measured facts (R1-R7 on this MI355X):
//  - any single read mechanism (vector x4/x1, nt, global_load_lds) caps at
//    ~5.4 B/cyc/CU (~3.3 TB/s chip), latency-insensitive.
//  - vector-MSHR pool and LDS-DMA queue are SEPARATE pools: both together
//    reach ~8 B/cyc/CU (~4.9 TB/s), kernel ~27us for 134 MB.
// R8 hypothesis: the scalar/SMEM path (K$ -> L2) is a THIRD independent
// request pool, never probed in R1-R7. Route 12.5% of both streams (the
// tail 1024 floats of each 8192-float row) through s_load_dwordx16 while
// the vector+DMA requests for the other 87.5% are in flight.
// Layout per block (= one T-row of 8192 floats):
//   chunk0 [0,4096):    a via nt-vector, b via global_load_lds (16 KB LDS)
//   chunk1 [4096,7168): a via nt-vector, b via global_load_lds (12 KB of same LDS)
//   scalar [7168,8192): a AND b via s_load_dwordx16, 8 rounds/wave of 32 floats
// Scalar data is wave-broadcast; all 64 lanes compute it redundantly and the
// contribution is scaled by 1/64 (exact) before the lane reduction.

#define T_MASK 8191
#define T_DIMF 8192.0f
#define FLOATS_PER_BLOCK 8192

typedef float vfloat4 __attribute__((ext_vector_type(4)));
typedef float sfloat16 __attribute__((ext_vector_type(16)));

__device__ __forceinline__ void load_lds16(const float* g, float* l) {
    __builtin_amdgcn_global_load_lds(
        (const __attribute__((address_space(1))) void*)g,
        (__attribute__((address_space(3))) void*)l,
        16 /*bytes per lane*/, 0 /*offset*/, 0 /*aux*/);
}

// One 64-byte scalar load through the K$ pool. p and byte_off must be
// wave-uniform (enforced via readfirstlane on the wave index upstream).
__device__ __forceinline__ sfloat16 sload16(const float* p, unsigned byte_off) {
    sfloat16 x;
    asm volatile("s_load_dwordx16 %0, %1, %2"
                 : "=s"(x)
                 : "s"(p), "s"(byte_off));
    return x;
}

__device__ __forceinline__ void swait_lgkm0() {
    asm volatile("s_waitcnt lgkmcnt(0)" ::: "memory");
    // rule-18: pin consumers after the wait (compiler would otherwise hoist
    // register-only FP ops above the inline-asm waitcnt).
    __builtin_amdgcn_sched_barrier(0);
}

// 32 floats of a and b via 4x s_load_dwordx16, weighted |a-b| partial.
// wbase = weight of the first element of this round.
__device__ __forceinline__ float scalar_round(const float* a, const float* b,
                                              unsigned off, float wbase) {
    sfloat16 x0 = sload16(a, off);
    sfloat16 x1 = sload16(a, off + 64u);
    sfloat16 y0 = sload16(b, off);
    sfloat16 y1 = sload16(b, off + 64u);
    swait_lgkm0();
    float s = 0.0f;
    #pragma unroll
    for (int j = 0; j < 16; ++j) {
        s += (wbase - (float)j)        * fabsf(x0[j] - y0[j]);
        s += (wbase - (float)(16 + j)) * fabsf(x1[j] - y1[j]);
    }
    return s;
}

__global__ __launch_bounds__(256)
void wl_partial_kernel(const float* __restrict__ a,
                       const float* __restrict__ b,
                       float* __restrict__ partial) {
    __shared__ float ldsB[4096];          // 16 KB

    const int tid  = threadIdx.x;
    const int lane = tid & 63;
    const int wave = tid >> 6;                       // 0..3
    const int wq   = __builtin_amdgcn_readfirstlane(wave);  // wave-uniform copy
    const int blockBase = blockIdx.x * FLOATS_PER_BLOCK;

    float acc  = 0.0f;   // per-lane (vector/DMA regions)
    float accS = 0.0f;   // wave-broadcast (scalar region), scaled 1/64 at end

    const vfloat4* a4 = (const vfloat4*)a;
    const unsigned sbase = (unsigned)(blockBase + 7168 + wq * 256) * 4u;

    // ---------------- phase 0: chunk0 = rows [0, 4096) ----------------
    {
        const int chunkBase = blockBase;

        // Path 1: DMA b-chunk into LDS (4 instrs/wave).
        #pragma unroll
        for (int s = 0; s < 4; ++s) {
            const int seg = wave * 1024 + s * 256;   // float offset (uniform)
            load_lds16(b + chunkBase + seg + lane * 4, &ldsB[seg]);
        }

        // Path 2: nt vector loads of the matching a-chunk.
        vfloat4 xa[4];
        const int c4 = chunkBase >> 2;
        #pragma unroll
        for (int k = 0; k < 4; ++k)
            xa[k] = __builtin_nontemporal_load(&a4[c4 + tid + k * 256]);

        // Path 3: scalar rounds 0..3 while both vmem paths are in flight.
        #pragma unroll
        for (int r = 0; r < 4; ++r) {
            const float wbase = (float)(1024 - wq * 256 - r * 32);
            accS += scalar_round(a, b, sbase + (unsigned)r * 128u, wbase);
        }

        __syncthreads();   // vmcnt(0) drain: DMA + vector complete

        #pragma unroll
        for (int k = 0; k < 4; ++k) {
            const int f4 = tid + k * 256;
            vfloat4 y = ((const vfloat4*)ldsB)[f4];
            const int g = chunkBase + f4 * 4;
            float w = T_DIMF - (float)(g & T_MASK);
            float d0 = fabsf(xa[k].x - y.x);
            float d1 = fabsf(xa[k].y - y.y);
            float d2 = fabsf(xa[k].z - y.z);
            float d3 = fabsf(xa[k].w - y.w);
            acc += w * (d0 + d1 + d2 + d3) - (d1 + 2.0f * d2 + 3.0f * d3);
        }
        __syncthreads();   // protect ldsB before phase-1 DMA
    }

    // ---------------- phase 1: chunk1 = rows [4096, 7168) ----------------
    {
        const int chunkBase = blockBase + 4096;

        #pragma unroll
        for (int s = 0; s < 3; ++s) {
            const int seg = wave * 768 + s * 256;
            load_lds16(b + chunkBase + seg + lane * 4, &ldsB[seg]);
        }

        vfloat4 xa[3];
        const int c4 = chunkBase >> 2;
        #pragma unroll
        for (int k = 0; k < 3; ++k)
            xa[k] = __builtin_nontemporal_load(&a4[c4 + tid + k * 256]);

        // scalar rounds 4..7
        #pragma unroll
        for (int r = 4; r < 8; ++r) {
            const float wbase = (float)(1024 - wq * 256 - r * 32);
            accS += scalar_round(a, b, sbase + (unsigned)r * 128u, wbase);
        }

        __syncthreads();

        #pragma unroll
        for (int k = 0; k < 3; ++k) {
            const int f4 = tid + k * 256;
            vfloat4 y = ((const vfloat4*)ldsB)[f4];
            const int g = chunkBase + f4 * 4;
            float w = T_DIMF - (float)(g & T_MASK);
            float d0 = fabsf(xa[k].x - y.x);
            float d1 = fabsf(xa[k].y - y.y);
            float d2 = fabsf(xa[k].z - y.z);
            float d3 = fabsf(xa[k].w - y.w);
            acc += w * (d0 + d1 + d2 + d3) - (d1 + 2.0f * d2 + 3.0f * d3);
        }
    }

    // fold wave-broadcast scalar contribution: each of the 64 lanes adds
    // accS/64, so the lane reduction recovers exactly accS per wave.
    acc += accS * 0.015625f;

    // wave-64 shuffle reduction
    #pragma unroll
    for (int off = 32; off > 0; off >>= 1)
        acc += __shfl_down(acc, off, 64);

    __shared__ float wave_sums[4];
    if (lane == 0) wave_sums[wave] = acc;
    __syncthreads();

    if (tid == 0)
        partial[blockIdx.x] = wave_sums[0] + wave_sums[1] + wave_sums[2] + wave_sums[3];
}

__global__ __launch_bounds__(256)
void wl_final_kernel(const float* __restrict__ partial, int n,
                     float* __restrict__ out, float scale) {
    float acc = 0.0f;
    for (int i = threadIdx.x; i < n; i += 256)
        acc += partial[i];

    #pragma unroll
    for (int off = 32; off > 0; off >>= 1)
        acc += __shfl_down(acc, off, 64);

    __shared__ float wave_sums[4];
    int lane = threadIdx.x & 63;
    int wave = threadIdx.x >> 6;
    if (lane == 0) wave_sums[wave] = acc;
    __syncthreads();

    if (threadIdx.x == 0)
        out[0] = (wave_sums[0] + wave_sums[1] + wave_sums[2] + wave_sums[3]) * scale;
}

extern "C" void kernel_launch(void* const* d_in, const int* in_sizes, int n_in,
                              void* d_out, int out_size, void* d_ws, size_t ws_size,
                              hipStream_t stream) {
    const float* a = (const float*)d_in[0];
    const float* b = (const float*)d_in[1];
    float* out = (float*)d_out;
    float* partial = (float*)d_ws;   // 2048 floats = 8 KB scratch

    int n = in_sizes[0];                     // 16,777,216
    int blocks = n / FLOATS_PER_BLOCK;       // 2048

    const long long T = 8192;
    const long long C = 64;
    const long long B = (long long)n / (C * T);
    float scale = (float)(2.0 / ((double)T * (double)C * (double)(T + 1) * (double)B));

    wl_partial_kernel<<<blocks, 256, 0, stream>>>(a, b, partial);
    wl_final_kernel<<<1, 256, 0, stream>>>(partial, blocks, out, scale);
}

// Round 2
// 130.452 us; speedup vs baseline: 1.1340x; 1.1340x over previous
//
#include <hip/hip_runtime.h>

// WassersteinLoss: out = scale * sum_{b,c,t} |a-b| * (T - t)
// R9: clean revert to R5, the measured best (131.8 us total; wl_partial ~27us).
// Measured facts (R1-R8 on this MI355X):
//  - any single read mechanism (vector x4/x1, nt, global_load_lds) caps at
//    ~5.4 B/cyc/CU (~3.3 TB/s chip), latency-insensitive (L3-warm == HBM).
//  - vector-MSHR pool and LDS-DMA queue are SEPARATE pools: driving both
//    concurrently reaches ~8 B/cyc/CU (~4.9 TB/s), kernel ~27us for 134 MB.
//  - barrier-free wave-local drains (R6) and nt-DMA + partial-vmcnt
//    pipelining (R7) do NOT beat this.
//  - R8 REFUTED the scalar/SMEM third-pool hypothesis: 8 serialized
//    s_load_dwordx16 rounds/wave put ~8x scalar-miss-latency on the critical
//    path (partial 27->44-51us, K$ thrash across 8 resident blocks/CU).
//    SMEM does not compose with the vector/DMA pools; the ~4.9 TB/s cap is
//    a downstream return-port limit, not a software-structure artifact.
//  - FETCH_SIZE (73.8 MB < 128 MiB input) shows ~45% of reads are L3 hits
//    despite the harness's 268 MB workspace re-poison sweeping L3.
// a read via nt vector loads; b read via global_load_lds DMA; both in
// flight before one __syncthreads drain. 2048 blocks x 256 thr, 16 KB LDS.

#define T_MASK 8191
#define T_DIMF 8192.0f

#define FLOATS_PER_BLOCK 8192
#define CHUNK_FLOATS 4096          // 16 KB LDS chunk of b per iteration
#define NITER (FLOATS_PER_BLOCK / CHUNK_FLOATS)   // 2

typedef float vfloat4 __attribute__((ext_vector_type(4)));

__device__ __forceinline__ void load_lds16(const float* g, float* l) {
    __builtin_amdgcn_global_load_lds(
        (const __attribute__((address_space(1))) void*)g,
        (__attribute__((address_space(3))) void*)l,
        16 /*bytes per lane*/, 0 /*offset*/, 0 /*aux*/);
}

__global__ __launch_bounds__(256)
void wl_partial_kernel(const float* __restrict__ a,
                       const float* __restrict__ b,
                       float* __restrict__ partial) {
    __shared__ float ldsB[CHUNK_FLOATS];

    const int tid  = threadIdx.x;
    const int lane = tid & 63;
    const int wave = tid >> 6;                   // 0..3
    const int blockBase = blockIdx.x * FLOATS_PER_BLOCK;

    float acc = 0.0f;

    for (int it = 0; it < NITER; ++it) {
        const int chunkBase = blockBase + it * CHUNK_FLOATS;

        // Path 1: DMA b-chunk into LDS (4 instrs/wave, 4 KB/wave in flight).
        // LDS dest is wave-uniform base; HW scatters lane i at base+16*i.
        #pragma unroll
        for (int s = 0; s < 4; ++s) {
            const int seg = wave * 1024 + s * 256;       // float offset (uniform)
            load_lds16(b + chunkBase + seg + lane * 4, &ldsB[seg]);
        }

        // Path 2: nt vector loads of the matching a-chunk into VGPRs
        // (4 instrs/thread, issued while the DMA is still in flight).
        vfloat4 xa[4];
        const vfloat4* a4 = (const vfloat4*)a;
        const int c4 = chunkBase >> 2;                   // float4 base of chunk
        #pragma unroll
        for (int k = 0; k < 4; ++k)
            xa[k] = __builtin_nontemporal_load(&a4[c4 + tid + k * 256]);

        __syncthreads();   // vmcnt(0) drain: both paths complete

        #pragma unroll
        for (int k = 0; k < 4; ++k) {
            const int f4 = tid + k * 256;                // float4 index in chunk
            vfloat4 y = ((const vfloat4*)ldsB)[f4];
            const int g = chunkBase + f4 * 4;            // global float idx of .x
            float w = T_DIMF - (float)(g & T_MASK);      // 4|T so no row wrap
            float d0 = fabsf(xa[k].x - y.x);
            float d1 = fabsf(xa[k].y - y.y);
            float d2 = fabsf(xa[k].z - y.z);
            float d3 = fabsf(xa[k].w - y.w);
            acc += w * (d0 + d1 + d2 + d3) - (d1 + 2.0f * d2 + 3.0f * d3);
        }
        __syncthreads();   // protect ldsB before next iteration's DMA
    }

    // wave-64 shuffle reduction
    #pragma unroll
    for (int off = 32; off > 0; off >>= 1)
        acc += __shfl_down(acc, off, 64);

    __shared__ float wave_sums[4];
    if (lane == 0) wave_sums[wave] = acc;
    __syncthreads();

    if (tid == 0)
        partial[blockIdx.x] = wave_sums[0] + wave_sums[1] + wave_sums[2] + wave_sums[3];
}

__global__ __launch_bounds__(256)
void wl_final_kernel(const float* __restrict__ partial, int n,
                     float* __restrict__ out, float scale) {
    float acc = 0.0f;
    for (int i = threadIdx.x; i < n; i += 256)
        acc += partial[i];

    #pragma unroll
    for (int off = 32; off > 0; off >>= 1)
        acc += __shfl_down(acc, off, 64);

    __shared__ float wave_sums[4];
    int lane = threadIdx.x & 63;
    int wave = threadIdx.x >> 6;
    if (lane == 0) wave_sums[wave] = acc;
    __syncthreads();

    if (threadIdx.x == 0)
        out[0] = (wave_sums[0] + wave_sums[1] + wave_sums[2] + wave_sums[3]) * scale;
}

extern "C" void kernel_launch(void* const* d_in, const int* in_sizes, int n_in,
                              void* d_out, int out_size, void* d_ws, size_t ws_size,
                              hipStream_t stream) {
    const float* a = (const float*)d_in[0];
    const float* b = (const float*)d_in[1];
    float* out = (float*)d_out;
    float* partial = (float*)d_ws;   // 2048 floats = 8 KB scratch

    int n = in_sizes[0];                     // 16,777,216
    int blocks = n / FLOATS_PER_BLOCK;       // 2048

    const long long T = 8192;
    const long long C = 64;
    const long long B = (long long)n / (C * T);
    float scale = (float)(2.0 / ((double)T * (double)C * (double)(T + 1) * (double)B));

    wl_partial_kernel<<<blocks, 256, 0, stream>>>(a, b, partial);
    wl_final_kernel<<<1, 256, 0, stream>>>(partial, blocks, out, scale);
}